// Round 21
// baseline (69.991 us; speedup 1.0000x reference)
//
#include <hip/hip_runtime.h>
#include <hip/hip_bf16.h>
#include <cstdint>
#include <cstddef>

// Problem constants (B=8, H=12, S=1024, D=64)
#define HH 12
#define BH 96          // B*H
#define SS 1024
#define DD 64
#define KT 64          // keys per KV tile
#define QB 128         // q rows per block (2 h-halves of 64; 32 q rows per wave)
#define NQT (SS / QB)  // 8

typedef __attribute__((ext_vector_type(2))) float f32x2;
typedef __attribute__((ext_vector_type(4))) float f32x4;
typedef __attribute__((ext_vector_type(8))) short bf16x8;
typedef __attribute__((ext_vector_type(4))) int   i32x4;

#define SCL  0.1803368801111204f   // 0.125 * log2(e)  -> exp2 domain
#define NEGL 1442695.0f            // 1e6  * log2(e)
#define THR  8.0f                  // defer-max threshold (log2 domain)

__device__ __forceinline__ unsigned int pk2(float lo, float hi) {
    __hip_bfloat162 h = __float22bfloat162_rn(float2{lo, hi});
    unsigned int u;
    __builtin_memcpy(&u, &h, sizeof(u));   // v_cvt_pk_bf16_f32
    return u;
}

// ===========================================================================
// Shared softmax / P-rebuild machinery (verified rounds 15-20)
// ===========================================================================
#define SOFTMAX_H(s, mr, lr, Oa, pk)                                          \
    do {                                                                      \
        float tmax;                                                           \
        {                                                                     \
            f32x4 mm = s[0];                                                  \
            _Pragma("unroll")                                                 \
            for (int n = 1; n < 4; ++n)                                       \
                _Pragma("unroll")                                             \
                for (int r = 0; r < 4; ++r) mm[r] = fmaxf(mm[r], s[n][r]);    \
            tmax = fmaxf(fmaxf(mm[0], mm[1]), fmaxf(mm[2], mm[3]));           \
        }                                                                     \
        tmax = fmaxf(tmax, __shfl_xor(tmax, 16));                             \
        tmax = fmaxf(tmax, __shfl_xor(tmax, 32));                             \
        if (!__all(tmax <= mr + THR)) {                                       \
            float mnew = fmaxf(mr, tmax);                                     \
            float corr = __builtin_amdgcn_exp2f(mr - mnew);                   \
            mr = mnew;                                                        \
            lr *= corr;                                                       \
            float cq[4];                                                      \
            _Pragma("unroll")                                                 \
            for (int r = 0; r < 4; ++r) cq[r] = __shfl(corr, 4 * g + r);      \
            _Pragma("unroll")                                                 \
            for (int dt = 0; dt < 4; ++dt)                                    \
                _Pragma("unroll")                                             \
                for (int r = 0; r < 4; ++r) Oa[dt][r] *= cq[r];               \
        }                                                                     \
        float tsum = 0.f;                                                     \
        _Pragma("unroll")                                                     \
        for (int n = 0; n < 4; ++n) {                                         \
            float p0 = __builtin_amdgcn_exp2f(s[n][0] - mr);                  \
            float p1 = __builtin_amdgcn_exp2f(s[n][1] - mr);                  \
            float p2 = __builtin_amdgcn_exp2f(s[n][2] - mr);                  \
            float p3 = __builtin_amdgcn_exp2f(s[n][3] - mr);                  \
            tsum += (p0 + p1) + (p2 + p3);                                    \
            pk[n][0] = pk2(p0, p1);                                           \
            pk[n][1] = pk2(p2, p3);                                           \
        }                                                                     \
        tsum += __shfl_xor(tsum, 16);                                         \
        tsum += __shfl_xor(tsum, 32);                                         \
        lr += tsum;                                                           \
    } while (0)

#define REBUILD_PA(pk, ks, pa)                                                \
    do {                                                                      \
        auto sw0 = __builtin_amdgcn_permlane32_swap(pk[2 * ks][0], pk[2 * ks + 1][0], false, false); \
        auto sw1 = __builtin_amdgcn_permlane32_swap(pk[2 * ks][1], pk[2 * ks + 1][1], false, false); \
        auto sp0 = __builtin_amdgcn_permlane16_swap(sw0[0], sw0[1], false, false); \
        auto sp1 = __builtin_amdgcn_permlane16_swap(sw1[0], sw1[1], false, false); \
        pa.u[0] = sp0[0];                                                     \
        pa.u[2] = sp0[1];                                                     \
        pa.u[1] = sp1[0];                                                     \
        pa.u[3] = sp1[1];                                                     \
    } while (0)

// QK^T both halves; MMSTMT sets f32x4 mm; KB0/KB1 are kb-load expressions.
#define QKT_BOTH(MMSTMT, KB0, KB1)                                            \
    __builtin_amdgcn_s_setprio(1);                                            \
    _Pragma("unroll")                                                         \
    for (int n = 0; n < 4; ++n) {                                             \
        f32x4 mm; MMSTMT;                                                     \
        bf16x8 kb0 = KB0;                                                     \
        bf16x8 kb1 = KB1;                                                     \
        f32x4 a0 = __builtin_amdgcn_mfma_f32_16x16x32_bf16(kb0, qa[0][0], mm, 0, 0, 0); \
        s40[n]   = __builtin_amdgcn_mfma_f32_16x16x32_bf16(kb1, qa[0][1], a0, 0, 0, 0); \
        f32x4 a1 = __builtin_amdgcn_mfma_f32_16x16x32_bf16(kb0, qa[1][0], mm, 0, 0, 0); \
        s41[n]   = __builtin_amdgcn_mfma_f32_16x16x32_bf16(kb1, qa[1][1], a1, 0, 0, 0); \
    }                                                                         \
    __builtin_amdgcn_s_setprio(0);

// softmax + joint PV for both halves; VB = vb-load expression.
#define SM_PV_BOTH(VB)                                                        \
    {                                                                         \
        unsigned int pk0[4][2], pk1[4][2];                                    \
        SOFTMAX_H(s40, m0, l0, Oacc0, pk0);                                   \
        SOFTMAX_H(s41, m1, l1, Oacc1, pk1);                                   \
        __builtin_amdgcn_s_setprio(1);                                        \
        _Pragma("unroll")                                                     \
        for (int ks = 0; ks < 2; ++ks) {                                      \
            union { bf16x8 v; unsigned int u[4]; } pa0, pa1;                  \
            REBUILD_PA(pk0, ks, pa0);                                         \
            REBUILD_PA(pk1, ks, pa1);                                         \
            _Pragma("unroll")                                                 \
            for (int dt = 0; dt < 4; ++dt) {                                  \
                bf16x8 vb = VB;                                               \
                Oacc0[dt] = __builtin_amdgcn_mfma_f32_16x16x32_bf16(pa0.v, vb, Oacc0[dt], 0, 0, 0); \
                Oacc1[dt] = __builtin_amdgcn_mfma_f32_16x16x32_bf16(pa1.v, vb, Oacc1[dt], 0, 0, 0); \
            }                                                                 \
        }                                                                     \
        __builtin_amdgcn_s_setprio(0);                                        \
    }

// ===========================================================================
// prep_idx: compact valid-key indices per batch (verified round 18/20).
// ===========================================================================
__global__ __launch_bounds__(256) void prep_idx_kernel(
        const int* __restrict__ mask,
        int* __restrict__ idxbuf,
        int* __restrict__ nvalid) {
    __shared__ int sc[256];
    const int b   = blockIdx.x;
    const int tid = threadIdx.x;
    i32x4 m = *(const i32x4*)(mask + b * SS + tid * 4);
    int keep[4];
    int c = 0;
#pragma unroll
    for (int j = 0; j < 4; ++j) { keep[j] = (m[j] != 0); c += keep[j]; }
    sc[tid] = c;
    __syncthreads();
    for (int off = 1; off < 256; off <<= 1) {
        int v = (tid >= off) ? sc[tid - off] : 0;
        __syncthreads();
        sc[tid] += v;
        __syncthreads();
    }
    const int total = sc[255];
    int pos = sc[tid] - c;
    int* dst = idxbuf + b * SS;
    if (total == 0) {
#pragma unroll
        for (int j = 0; j < 4; ++j) dst[tid * 4 + j] = tid * 4 + j;
        if (tid == 0) nvalid[b] = SS;
        return;
    }
#pragma unroll
    for (int j = 0; j < 4; ++j)
        if (keep[j]) dst[pos++] = tid * 4 + j;
    const int padded = (total + 63) & ~63;
    for (int s = total + tid; s < padded; s += 256) dst[s] = 0;
    if (tid == 0) nvalid[b] = total;
}

// ===========================================================================
// prep_kv: gather compacted K rows -> Kc[bh][slot][d] (bf16), and build the
// compacted TRANSPOSED V -> VcT[bh][d][slot] (bf16, row stride 1024).
// One block per (bh, 64-slot tile); blocks past the padded count exit.
// ===========================================================================
__global__ __launch_bounds__(256) void prep_kv_kernel(
        const float* __restrict__ Kb,
        const float* __restrict__ Vb,
        const int* __restrict__ idxbuf,
        const int* __restrict__ nvalid,
        unsigned short* __restrict__ Kc,
        unsigned short* __restrict__ VcT) {
    __shared__ unsigned short vt[64][72];   // bf16 [slot][d], padded rows
    const int bh = blockIdx.x;
    const int t  = blockIdx.y;
    const int b  = bh / HH;
    const int padded = (nvalid[b] + 63) & ~63;
    if (t * KT >= padded) return;           // block-uniform exit (before barrier)

    const int tid = threadIdx.x;
    const int r   = tid >> 2;               // slot within tile
    const int d0  = (tid & 3) * 16;         // 16-d chunk
    const int slot = t * KT + r;
    const int krow = idxbuf[b * SS + slot];

    {   // K row: f32 -> bf16, straight copy to compacted layout
        const float* kp = Kb + ((size_t)(bh * SS + krow)) * DD + d0;
        f32x4 x0 = *(const f32x4*)(kp + 0);
        f32x4 x1 = *(const f32x4*)(kp + 4);
        f32x4 x2 = *(const f32x4*)(kp + 8);
        f32x4 x3 = *(const f32x4*)(kp + 12);
        union { bf16x8 v; unsigned int u[4]; } o0, o1;
        o0.u[0] = pk2(x0[0], x0[1]); o0.u[1] = pk2(x0[2], x0[3]);
        o0.u[2] = pk2(x1[0], x1[1]); o0.u[3] = pk2(x1[2], x1[3]);
        o1.u[0] = pk2(x2[0], x2[1]); o1.u[1] = pk2(x2[2], x2[3]);
        o1.u[2] = pk2(x3[0], x3[1]); o1.u[3] = pk2(x3[2], x3[3]);
        unsigned short* dst = Kc + ((size_t)(bh * SS + slot)) * DD + d0;
        *(bf16x8*)(dst)     = o0.v;
        *(bf16x8*)(dst + 8) = o1.v;
    }
    {   // V row: f32 -> bf16 into LDS staging tile
        const float* vp = Vb + ((size_t)(bh * SS + krow)) * DD + d0;
        f32x4 x0 = *(const f32x4*)(vp + 0);
        f32x4 x1 = *(const f32x4*)(vp + 4);
        f32x4 x2 = *(const f32x4*)(vp + 8);
        f32x4 x3 = *(const f32x4*)(vp + 12);
        union { bf16x8 v; unsigned int u[4]; } o0, o1;
        o0.u[0] = pk2(x0[0], x0[1]); o0.u[1] = pk2(x0[2], x0[3]);
        o0.u[2] = pk2(x1[0], x1[1]); o0.u[3] = pk2(x1[2], x1[3]);
        o1.u[0] = pk2(x2[0], x2[1]); o1.u[1] = pk2(x2[2], x2[3]);
        o1.u[2] = pk2(x3[0], x3[1]); o1.u[3] = pk2(x3[2], x3[3]);
        *(bf16x8*)&vt[r][d0]     = o0.v;
        *(bf16x8*)&vt[r][d0 + 8] = o1.v;
    }
    __syncthreads();
    {   // transpose out: VcT[bh][d][t*64 + k]
        const int d  = tid >> 2;
        const int k0 = (tid & 3) * 16;
        bf16x8 a, bvec;
#pragma unroll
        for (int j = 0; j < 8; ++j) a[j]    = (short)vt[k0 + j][d];
#pragma unroll
        for (int j = 0; j < 8; ++j) bvec[j] = (short)vt[k0 + 8 + j][d];
        unsigned short* dst = VcT + ((size_t)(bh * DD + d)) * SS + t * KT + k0;
        *(bf16x8*)(dst)     = a;
        *(bf16x8*)(dst + 8) = bvec;
    }
}

// ===========================================================================
// attn_direct: NO LDS, NO barriers. MFMA fragments loaded straight from the
// compacted bf16 Kc / transposed VcT (L2-resident per XCD via bh-affinity).
// ===========================================================================
__global__ __launch_bounds__(256, 3) void attn_direct_kernel(
        const float* __restrict__ Q,
        const unsigned short* __restrict__ Kc,
        const unsigned short* __restrict__ VcT,
        const int* __restrict__ nvalid,
        float* __restrict__ Out) {
    const int tid  = threadIdx.x;
    const int w    = tid >> 6;
    const int lane = tid & 63;
    const int g    = lane >> 4;
    const int l15  = lane & 15;

    const int bh = blockIdx.x;
    const int qt = blockIdx.y;
    const int b  = bh / HH;

    const int nv  = nvalid[b];
    const int NTb = (nv + 63) >> 6;

    // ---- Q fragments (B-operand of swapped QK^T), both halves, scaled ----
    bf16x8 qa[2][2];
#pragma unroll
    for (int h = 0; h < 2; ++h) {
        const float* qp = Q + ((size_t)(bh * SS + qt * QB + h * 64 + w * 16 + l15)) * DD + 8 * g;
#pragma unroll
        for (int c = 0; c < 2; ++c) {
            f32x4 lo = *(const f32x4*)(qp + c * 32);
            f32x4 hi = *(const f32x4*)(qp + c * 32 + 4);
            union { bf16x8 v; unsigned int u[4]; } o;
            o.u[0] = pk2(lo[0] * SCL, lo[1] * SCL);
            o.u[1] = pk2(lo[2] * SCL, lo[3] * SCL);
            o.u[2] = pk2(hi[0] * SCL, hi[1] * SCL);
            o.u[3] = pk2(hi[2] * SCL, hi[3] * SCL);
            qa[h][c] = o.v;
        }
    }

    const unsigned short* Kbase = Kc  + (size_t)bh * SS * DD;
    const unsigned short* Vbase = VcT + (size_t)bh * DD * SS;

    f32x4 Oacc0[4], Oacc1[4];
#pragma unroll
    for (int dt = 0; dt < 4; ++dt) {
        Oacc0[dt] = (f32x4){0.f, 0.f, 0.f, 0.f};
        Oacc1[dt] = (f32x4){0.f, 0.f, 0.f, 0.f};
    }
    float m0 = -3.0e38f, m1 = -3.0e38f, l0 = 0.f, l1 = 0.f;

    // ---- main loop: tiles 0 .. NTb-2 (zero C-init; no barriers at all) ----
    for (int t = 0; t < NTb - 1; ++t) {
        f32x4 s40[4], s41[4];
        QKT_BOTH({ mm[0] = 0.0f; mm[1] = 0.0f; mm[2] = 0.0f; mm[3] = 0.0f; },
                 (*(const bf16x8*)(Kbase + (size_t)(t * KT + 16 * n + l15) * DD + 8 * g)),
                 (*(const bf16x8*)(Kbase + (size_t)(t * KT + 16 * n + l15) * DD + 32 + 8 * g)));
        SM_PV_BOTH((*(const bf16x8*)(Vbase + (size_t)(dt * 16 + l15) * SS + t * KT + ks * 32 + 8 * g)));
    }

    // ---- peeled last tile: padded slots get -NEGL in the C-init ----
    {
        const int t = NTb - 1;
        const int lastbase = t * KT + 4 * g;
        f32x4 s40[4], s41[4];
        QKT_BOTH({
            int slot = lastbase + 16 * n;
            mm[0] = (slot + 0 < nv) ? 0.0f : -NEGL;
            mm[1] = (slot + 1 < nv) ? 0.0f : -NEGL;
            mm[2] = (slot + 2 < nv) ? 0.0f : -NEGL;
            mm[3] = (slot + 3 < nv) ? 0.0f : -NEGL;
        },
                 (*(const bf16x8*)(Kbase + (size_t)(t * KT + 16 * n + l15) * DD + 8 * g)),
                 (*(const bf16x8*)(Kbase + (size_t)(t * KT + 16 * n + l15) * DD + 32 + 8 * g)));
        SM_PV_BOTH((*(const bf16x8*)(Vbase + (size_t)(dt * 16 + l15) * SS + t * KT + ks * 32 + 8 * g)));
    }

    // ---- epilogue ----
#pragma unroll
    for (int h = 0; h < 2; ++h) {
        float inv = 1.0f / (h ? l1 : l0);
        float invq[4];
#pragma unroll
        for (int r = 0; r < 4; ++r) invq[r] = __shfl(inv, 4 * g + r);
        const size_t rowbase = (size_t)(bh * SS + qt * QB + h * 64 + w * 16);
#pragma unroll
        for (int dt = 0; dt < 4; ++dt)
#pragma unroll
            for (int r = 0; r < 4; ++r)
                Out[(rowbase + 4 * g + r) * DD + dt * 16 + l15] =
                    (h ? Oacc1[dt][r] : Oacc0[dt][r]) * invq[r];
    }
}

// ===========================================================================
// attn_staged: round-20 verified fallback (LDS staging, used if ws too small)
// ===========================================================================
__global__ __launch_bounds__(256, 3) void attn_staged_kernel(
        const float* __restrict__ Q,
        const float* __restrict__ Kb,
        const float* __restrict__ Vb,
        const int* __restrict__ idxbuf,
        const int* __restrict__ nvalid,
        float* __restrict__ Out) {
    __shared__ unsigned short Klds[KT * DD];
    __shared__ unsigned short Vlds[DD * KT];
    __shared__ int idxLds[SS];

    const int tid  = threadIdx.x;
    const int w    = tid >> 6;
    const int lane = tid & 63;
    const int g    = lane >> 4;
    const int l15  = lane & 15;
    const int swq  = (l15 & 7) << 3;

    const int bh = blockIdx.x;
    const int qt = blockIdx.y;
    const int b  = bh / HH;

    ((i32x4*)idxLds)[tid] = ((const i32x4*)(idxbuf + b * SS))[tid];
    const int nv  = nvalid[b];
    const int NTb = (nv + 63) >> 6;

    bf16x8 qa[2][2];
#pragma unroll
    for (int h = 0; h < 2; ++h) {
        const float* qp = Q + ((size_t)(bh * SS + qt * QB + h * 64 + w * 16 + l15)) * DD + 8 * g;
#pragma unroll
        for (int c = 0; c < 2; ++c) {
            f32x4 lo = *(const f32x4*)(qp + c * 32);
            f32x4 hi = *(const f32x4*)(qp + c * 32 + 4);
            union { bf16x8 v; unsigned int u[4]; } o;
            o.u[0] = pk2(lo[0] * SCL, lo[1] * SCL);
            o.u[1] = pk2(lo[2] * SCL, lo[3] * SCL);
            o.u[2] = pk2(hi[0] * SCL, hi[1] * SCL);
            o.u[3] = pk2(hi[2] * SCL, hi[3] * SCL);
            qa[h][c] = o.v;
        }
    }

    f32x4 kreg[2][2];
    f32x2 vreg[8];
    const int vd0 = (tid & 31) * 2;
    const int vk0 = (tid >> 5) * 8;
    auto load_tile_regs = [&](int t) {
#pragma unroll
        for (int i = 0; i < 2; ++i) {
            int c = tid + i * 256;
            int row = c >> 3, d0 = (c & 7) * 8;
            int krow = idxLds[t * KT + row];
            const float* kp = Kb + ((size_t)(bh * SS + krow)) * DD + d0;
            kreg[i][0] = *(const f32x4*)kp;
            kreg[i][1] = *(const f32x4*)(kp + 4);
        }
        {
            i32x4 vi0 = *(const i32x4*)&idxLds[t * KT + vk0];
            i32x4 vi1 = *(const i32x4*)&idxLds[t * KT + vk0 + 4];
            const float* vbase = Vb + (size_t)(bh * SS) * DD + vd0;
#pragma unroll
            for (int j = 0; j < 4; ++j) vreg[j]     = *(const f32x2*)(vbase + (size_t)vi0[j] * DD);
#pragma unroll
            for (int j = 0; j < 4; ++j) vreg[4 + j] = *(const f32x2*)(vbase + (size_t)vi1[j] * DD);
        }
    };
    auto write_tile_lds = [&]() {
#pragma unroll
        for (int i = 0; i < 2; ++i) {
            int c = tid + i * 256;
            int row = c >> 3, d0 = (c & 7) * 8;
            union { bf16x8 v; unsigned int u[4]; } kv;
            kv.u[0] = pk2(kreg[i][0][0], kreg[i][0][1]);
            kv.u[1] = pk2(kreg[i][0][2], kreg[i][0][3]);
            kv.u[2] = pk2(kreg[i][1][0], kreg[i][1][1]);
            kv.u[3] = pk2(kreg[i][1][2], kreg[i][1][3]);
            *(bf16x8*)&Klds[row * DD + (d0 ^ ((row & 7) << 3))] = kv.v;
        }
        {
            union { bf16x8 v; unsigned int u[4]; } v0, v1;
            v0.u[0] = pk2(vreg[0][0], vreg[1][0]);
            v0.u[1] = pk2(vreg[2][0], vreg[3][0]);
            v0.u[2] = pk2(vreg[4][0], vreg[5][0]);
            v0.u[3] = pk2(vreg[6][0], vreg[7][0]);
            v1.u[0] = pk2(vreg[0][1], vreg[1][1]);
            v1.u[1] = pk2(vreg[2][1], vreg[3][1]);
            v1.u[2] = pk2(vreg[4][1], vreg[5][1]);
            v1.u[3] = pk2(vreg[6][1], vreg[7][1]);
            *(bf16x8*)&Vlds[vd0 * KT + (vk0 ^ ((vd0 & 7) << 3))] = v0.v;
            *(bf16x8*)&Vlds[(vd0 + 1) * KT + (vk0 ^ (((vd0 + 1) & 7) << 3))] = v1.v;
        }
    };

    f32x4 Oacc0[4], Oacc1[4];
#pragma unroll
    for (int dt = 0; dt < 4; ++dt) {
        Oacc0[dt] = (f32x4){0.f, 0.f, 0.f, 0.f};
        Oacc1[dt] = (f32x4){0.f, 0.f, 0.f, 0.f};
    }
    float m0 = -3.0e38f, m1 = -3.0e38f, l0 = 0.f, l1 = 0.f;

    __syncthreads();
    load_tile_regs(0);

    for (int t = 0; t < NTb - 1; ++t) {
        __syncthreads();
        write_tile_lds();
        __syncthreads();
        load_tile_regs(t + 1);

        f32x4 s40[4], s41[4];
        QKT_BOTH({ mm[0] = 0.0f; mm[1] = 0.0f; mm[2] = 0.0f; mm[3] = 0.0f; },
                 (*(const bf16x8*)&Klds[(16 * n + l15) * DD + ((8 * g) ^ swq)]),
                 (*(const bf16x8*)&Klds[(16 * n + l15) * DD + ((32 + 8 * g) ^ swq)]));
        SM_PV_BOTH((*(const bf16x8*)&Vlds[(dt * 16 + l15) * KT + ((ks * 32 + 8 * g) ^ swq)]));
    }

    {
        __syncthreads();
        write_tile_lds();
        __syncthreads();

        const int lastbase = (NTb - 1) * KT + 4 * g;
        f32x4 s40[4], s41[4];
        QKT_BOTH({
            int slot = lastbase + 16 * n;
            mm[0] = (slot + 0 < nv) ? 0.0f : -NEGL;
            mm[1] = (slot + 1 < nv) ? 0.0f : -NEGL;
            mm[2] = (slot + 2 < nv) ? 0.0f : -NEGL;
            mm[3] = (slot + 3 < nv) ? 0.0f : -NEGL;
        },
                 (*(const bf16x8*)&Klds[(16 * n + l15) * DD + ((8 * g) ^ swq)]),
                 (*(const bf16x8*)&Klds[(16 * n + l15) * DD + ((32 + 8 * g) ^ swq)]));
        SM_PV_BOTH((*(const bf16x8*)&Vlds[(dt * 16 + l15) * KT + ((ks * 32 + 8 * g) ^ swq)]));
    }

#pragma unroll
    for (int h = 0; h < 2; ++h) {
        float inv = 1.0f / (h ? l1 : l0);
        float invq[4];
#pragma unroll
        for (int r = 0; r < 4; ++r) invq[r] = __shfl(inv, 4 * g + r);
        const size_t rowbase = (size_t)(bh * SS + qt * QB + h * 64 + w * 16);
#pragma unroll
        for (int dt = 0; dt < 4; ++dt)
#pragma unroll
            for (int r = 0; r < 4; ++r)
                Out[(rowbase + 4 * g + r) * DD + dt * 16 + l15] =
                    (h ? Oacc1[dt][r] : Oacc0[dt][r]) * invq[r];
    }
}

extern "C" void kernel_launch(void* const* d_in, const int* in_sizes, int n_in,
                              void* d_out, int out_size, void* d_ws, size_t ws_size,
                              hipStream_t stream) {
    const float* Q   = (const float*)d_in[0];
    const float* K   = (const float*)d_in[1];
    const float* V   = (const float*)d_in[2];
    const int* mask  = (const int*)d_in[5];
    float* out       = (float*)d_out;

    int* idxbuf = (int*)d_ws;                    // 8*1024 ints = 32 KB
    int* nvalid = idxbuf + 8 * SS;               // +16 ints (64 B, aligned)

    const size_t kc_elems = (size_t)BH * SS * DD;           // 6.29M bf16
    const size_t need = 8 * SS * 4 + 64 + 2 * kc_elems * 2; // ~25.2 MB

    prep_idx_kernel<<<dim3(8), 256, 0, stream>>>(mask, idxbuf, nvalid);

    if (ws_size >= need) {
        unsigned short* Kc  = (unsigned short*)(nvalid + 16);
        unsigned short* VcT = Kc + kc_elems;
        prep_kv_kernel<<<dim3(BH, SS / KT), 256, 0, stream>>>(K, V, idxbuf, nvalid, Kc, VcT);
        attn_direct_kernel<<<dim3(BH, NQT), 256, 0, stream>>>(Q, Kc, VcT, nvalid, out);
    } else {
        attn_staged_kernel<<<dim3(BH, NQT), 256, 0, stream>>>(Q, K, V, idxbuf, nvalid, out);
    }
}

// Round 22
// 47.892 us; speedup vs baseline: 1.4614x; 1.4614x over previous
//
#include <hip/hip_runtime.h>
#include <hip/hip_bf16.h>
#include <cstdint>
#include <cstddef>

// Problem constants (B=8, H=12, S=1024, D=64)
#define HH 12
#define BH 96          // B*H
#define SS 1024
#define DD 64
#define KT 64          // keys per KV tile
#define QB 64          // q rows per block (16 per wave) -> grid 1536 = 6 blk/CU
#define NQT (SS / QB)  // 16

typedef __attribute__((ext_vector_type(2))) float f32x2;
typedef __attribute__((ext_vector_type(4))) float f32x4;
typedef __attribute__((ext_vector_type(8))) short bf16x8;
typedef __attribute__((ext_vector_type(4))) int   i32x4;

#define SCL  0.1803368801111204f   // 0.125 * log2(e)  -> exp2 domain
#define NEGL 1442695.0f            // 1e6  * log2(e)
#define THR  8.0f                  // defer-max threshold (log2 domain)

__device__ __forceinline__ unsigned int pk2(float lo, float hi) {
    __hip_bfloat162 h = __float22bfloat162_rn(float2{lo, hi});
    unsigned int u;
    __builtin_memcpy(&u, &h, sizeof(u));   // v_cvt_pk_bf16_f32
    return u;
}

// ===========================================================================
// prep_idx: compact valid-key indices per batch (verified rounds 18/20).
// Masked keys contribute EXACTLY 0 in the f32 reference (exp(-1e6) == 0.0f).
// All-masked edge case: identity mapping + nvalid=SS (shift-invariance).
// ===========================================================================
__global__ __launch_bounds__(256) void prep_idx_kernel(
        const int* __restrict__ mask,
        int* __restrict__ idxbuf,
        int* __restrict__ nvalid) {
    __shared__ int sc[256];
    const int b   = blockIdx.x;
    const int tid = threadIdx.x;
    i32x4 m = *(const i32x4*)(mask + b * SS + tid * 4);
    int keep[4];
    int c = 0;
#pragma unroll
    for (int j = 0; j < 4; ++j) { keep[j] = (m[j] != 0); c += keep[j]; }
    sc[tid] = c;
    __syncthreads();
    for (int off = 1; off < 256; off <<= 1) {
        int v = (tid >= off) ? sc[tid - off] : 0;
        __syncthreads();
        sc[tid] += v;
        __syncthreads();
    }
    const int total = sc[255];
    int pos = sc[tid] - c;
    int* dst = idxbuf + b * SS;
    if (total == 0) {
#pragma unroll
        for (int j = 0; j < 4; ++j) dst[tid * 4 + j] = tid * 4 + j;
        if (tid == 0) nvalid[b] = SS;
        return;
    }
#pragma unroll
    for (int j = 0; j < 4; ++j)
        if (keep[j]) dst[pos++] = tid * 4 + j;
    const int padded = (total + 63) & ~63;
    for (int s = total + tid; s < padded; s += 256) dst[s] = 0;
    if (tid == 0) nvalid[b] = total;
}

// ===========================================================================
// Flash attention over COMPACTED valid keys. Round-20 verified pipeline with
// ONE change: QB 128 -> 64 (single h-half per block). Grid = (bh, 16) = 1536
// blocks = 6 blocks/CU = 24 waves/CU (was 3/12) — occupancy test for the
// latency-bound hypothesis. Everything else identical: swapped QK^T, P
// in-register (permlane32+16 swap), defer-max, mask in MFMA C-init, peeled
// last tile, LDS swizzle col ^ ((row&7)<<3), schedule
// {barrier; write LDS(t); barrier; load(t+1); compute(t)}.
// ===========================================================================
__global__ __launch_bounds__(256, 4) void attn_kernel(
        const float* __restrict__ Q,
        const float* __restrict__ Kb,
        const float* __restrict__ Vb,
        const int* __restrict__ idxbuf,
        const int* __restrict__ nvalid,
        float* __restrict__ Out) {
    __shared__ unsigned short Klds[KT * DD];     // 8 KB
    __shared__ unsigned short Vlds[DD * KT];     // 8 KB
    __shared__ int idxLds[SS];                   // 4 KB

    const int tid  = threadIdx.x;
    const int w    = tid >> 6;
    const int lane = tid & 63;
    const int g    = lane >> 4;
    const int l15  = lane & 15;
    const int swq  = (l15 & 7) << 3;

    const int bh = blockIdx.x;
    const int qt = blockIdx.y;
    const int b  = bh / HH;

    // ---- compacted-index table (once per block) ----
    ((i32x4*)idxLds)[tid] = ((const i32x4*)(idxbuf + b * SS))[tid];
    const int nv  = nvalid[b];
    const int NTb = (nv + 63) >> 6;

    // ---- Q fragments (B-operand of swapped QK^T), scaled, exp2 domain ----
    bf16x8 qa[2];
    {
        const float* qp = Q + ((size_t)(bh * SS + qt * QB + w * 16 + l15)) * DD + 8 * g;
#pragma unroll
        for (int c = 0; c < 2; ++c) {
            f32x4 lo = *(const f32x4*)(qp + c * 32);
            f32x4 hi = *(const f32x4*)(qp + c * 32 + 4);
            union { bf16x8 v; unsigned int u[4]; } o;
            o.u[0] = pk2(lo[0] * SCL, lo[1] * SCL);
            o.u[1] = pk2(lo[2] * SCL, lo[3] * SCL);
            o.u[2] = pk2(hi[0] * SCL, hi[1] * SCL);
            o.u[3] = pk2(hi[2] * SCL, hi[3] * SCL);
            qa[c] = o.v;
        }
    }

    // ---- staging registers (verified layout, gathered rows) ----
    f32x4 kreg[2][2];
    f32x2 vreg[8];                       // vreg[j] = V[key(vk0+j)][vd0..vd0+1]
    const int vd0 = (tid & 31) * 2;      // d-pair
    const int vk0 = (tid >> 5) * 8;      // 8-slot run
    auto load_tile_regs = [&](int t) {
#pragma unroll
        for (int i = 0; i < 2; ++i) {
            int c = tid + i * 256;       // K[slot][d0..d0+7]; row gathered via idxLds
            int row = c >> 3, d0 = (c & 7) * 8;
            int krow = idxLds[t * KT + row];
            const float* kp = Kb + ((size_t)(bh * SS + krow)) * DD + d0;
            kreg[i][0] = *(const f32x4*)kp;
            kreg[i][1] = *(const f32x4*)(kp + 4);
        }
        {   // V: 8 x f32x2 at gathered rows (each 256B row shared by 32 lanes)
            i32x4 vi0 = *(const i32x4*)&idxLds[t * KT + vk0];
            i32x4 vi1 = *(const i32x4*)&idxLds[t * KT + vk0 + 4];
            const float* vbase = Vb + (size_t)(bh * SS) * DD + vd0;
#pragma unroll
            for (int j = 0; j < 4; ++j) vreg[j]     = *(const f32x2*)(vbase + (size_t)vi0[j] * DD);
#pragma unroll
            for (int j = 0; j < 4; ++j) vreg[4 + j] = *(const f32x2*)(vbase + (size_t)vi1[j] * DD);
        }
    };
    auto write_tile_lds = [&]() {
#pragma unroll
        for (int i = 0; i < 2; ++i) {
            int c = tid + i * 256;
            int row = c >> 3, d0 = (c & 7) * 8;
            union { bf16x8 v; unsigned int u[4]; } kv;
            kv.u[0] = pk2(kreg[i][0][0], kreg[i][0][1]);
            kv.u[1] = pk2(kreg[i][0][2], kreg[i][0][3]);
            kv.u[2] = pk2(kreg[i][1][0], kreg[i][1][1]);
            kv.u[3] = pk2(kreg[i][1][2], kreg[i][1][3]);
            *(bf16x8*)&Klds[row * DD + (d0 ^ ((row & 7) << 3))] = kv.v;
        }
        {   // two V rows (d = vd0, vd0+1), slots vk0..vk0+7
            union { bf16x8 v; unsigned int u[4]; } v0, v1;
            v0.u[0] = pk2(vreg[0][0], vreg[1][0]);
            v0.u[1] = pk2(vreg[2][0], vreg[3][0]);
            v0.u[2] = pk2(vreg[4][0], vreg[5][0]);
            v0.u[3] = pk2(vreg[6][0], vreg[7][0]);
            v1.u[0] = pk2(vreg[0][1], vreg[1][1]);
            v1.u[1] = pk2(vreg[2][1], vreg[3][1]);
            v1.u[2] = pk2(vreg[4][1], vreg[5][1]);
            v1.u[3] = pk2(vreg[6][1], vreg[7][1]);
            *(bf16x8*)&Vlds[vd0 * KT + (vk0 ^ ((vd0 & 7) << 3))] = v0.v;
            *(bf16x8*)&Vlds[(vd0 + 1) * KT + (vk0 ^ (((vd0 + 1) & 7) << 3))] = v1.v;
        }
    };

    f32x4 Oacc0[4];
#pragma unroll
    for (int dt = 0; dt < 4; ++dt) Oacc0[dt] = (f32x4){0.f, 0.f, 0.f, 0.f};
    float m0 = -3.0e38f, l0 = 0.f;

    __syncthreads();                     // idxLds visible to all waves
    load_tile_regs(0);

// softmax: s -> pk (bf16-packed P), updates mr/lr/Oa (verified r15-r20)
#define SOFTMAX_H(s, mr, lr, Oa, pk)                                          \
    do {                                                                      \
        float tmax;                                                           \
        {                                                                     \
            f32x4 mm = s[0];                                                  \
            _Pragma("unroll")                                                 \
            for (int n = 1; n < 4; ++n)                                       \
                _Pragma("unroll")                                             \
                for (int r = 0; r < 4; ++r) mm[r] = fmaxf(mm[r], s[n][r]);    \
            tmax = fmaxf(fmaxf(mm[0], mm[1]), fmaxf(mm[2], mm[3]));           \
        }                                                                     \
        tmax = fmaxf(tmax, __shfl_xor(tmax, 16));                             \
        tmax = fmaxf(tmax, __shfl_xor(tmax, 32));                             \
        if (!__all(tmax <= mr + THR)) {                                       \
            float mnew = fmaxf(mr, tmax);                                     \
            float corr = __builtin_amdgcn_exp2f(mr - mnew);                   \
            mr = mnew;                                                        \
            lr *= corr;                                                       \
            float cq[4];                                                      \
            _Pragma("unroll")                                                 \
            for (int r = 0; r < 4; ++r) cq[r] = __shfl(corr, 4 * g + r);      \
            _Pragma("unroll")                                                 \
            for (int dt = 0; dt < 4; ++dt)                                    \
                _Pragma("unroll")                                             \
                for (int r = 0; r < 4; ++r) Oa[dt][r] *= cq[r];               \
        }                                                                     \
        float tsum = 0.f;                                                     \
        _Pragma("unroll")                                                     \
        for (int n = 0; n < 4; ++n) {                                         \
            float p0 = __builtin_amdgcn_exp2f(s[n][0] - mr);                  \
            float p1 = __builtin_amdgcn_exp2f(s[n][1] - mr);                  \
            float p2 = __builtin_amdgcn_exp2f(s[n][2] - mr);                  \
            float p3 = __builtin_amdgcn_exp2f(s[n][3] - mr);                  \
            tsum += (p0 + p1) + (p2 + p3);                                    \
            pk[n][0] = pk2(p0, p1);                                           \
            pk[n][1] = pk2(p2, p3);                                           \
        }                                                                     \
        tsum += __shfl_xor(tsum, 16);                                         \
        tsum += __shfl_xor(tsum, 32);                                         \
        lr += tsum;                                                           \
    } while (0)

// rebuild PV A-fragment (permlane32_swap + permlane16_swap, verified r15)
#define REBUILD_PA(pk, ks, pa)                                                \
    do {                                                                      \
        auto sw0 = __builtin_amdgcn_permlane32_swap(pk[2 * ks][0], pk[2 * ks + 1][0], false, false); \
        auto sw1 = __builtin_amdgcn_permlane32_swap(pk[2 * ks][1], pk[2 * ks + 1][1], false, false); \
        auto sp0 = __builtin_amdgcn_permlane16_swap(sw0[0], sw0[1], false, false); \
        auto sp1 = __builtin_amdgcn_permlane16_swap(sw1[0], sw1[1], false, false); \
        pa.u[0] = sp0[0];                                                     \
        pa.u[2] = sp0[1];                                                     \
        pa.u[1] = sp1[0];                                                     \
        pa.u[3] = sp1[1];                                                     \
    } while (0)

// QK^T (swapped, single h); MMSTMT sets f32x4 mm (the MFMA C-init)
#define QKT_ONE(MMSTMT)                                                       \
    __builtin_amdgcn_s_setprio(1);                                            \
    _Pragma("unroll")                                                         \
    for (int n = 0; n < 4; ++n) {                                             \
        f32x4 mm; MMSTMT;                                                     \
        bf16x8 kb0 = *(const bf16x8*)&Klds[(16 * n + l15) * DD + ((8 * g) ^ swq)]; \
        bf16x8 kb1 = *(const bf16x8*)&Klds[(16 * n + l15) * DD + ((32 + 8 * g) ^ swq)]; \
        f32x4 a0 = __builtin_amdgcn_mfma_f32_16x16x32_bf16(kb0, qa[0], mm, 0, 0, 0); \
        s40[n]   = __builtin_amdgcn_mfma_f32_16x16x32_bf16(kb1, qa[1], a0, 0, 0, 0); \
    }                                                                         \
    __builtin_amdgcn_s_setprio(0);

// softmax + PV (single h)
#define SM_PV_ONE()                                                           \
    {                                                                         \
        unsigned int pk0[4][2];                                               \
        SOFTMAX_H(s40, m0, l0, Oacc0, pk0);                                   \
        __builtin_amdgcn_s_setprio(1);                                        \
        _Pragma("unroll")                                                     \
        for (int ks = 0; ks < 2; ++ks) {                                      \
            union { bf16x8 v; unsigned int u[4]; } pa0;                       \
            REBUILD_PA(pk0, ks, pa0);                                         \
            _Pragma("unroll")                                                 \
            for (int dt = 0; dt < 4; ++dt) {                                  \
                bf16x8 vb = *(const bf16x8*)                                  \
                    &Vlds[(dt * 16 + l15) * KT + ((ks * 32 + 8 * g) ^ swq)];  \
                Oacc0[dt] = __builtin_amdgcn_mfma_f32_16x16x32_bf16(pa0.v, vb, Oacc0[dt], 0, 0, 0); \
            }                                                                 \
        }                                                                     \
        __builtin_amdgcn_s_setprio(0);                                        \
    }

    // ---- main loop: tiles 0 .. NTb-2, zero C-init, unconditional prefetch ----
    for (int t = 0; t < NTb - 1; ++t) {
        __syncthreads();                 // all waves done reading tile t-1
        write_tile_lds();
        __syncthreads();                 // tile t visible
        load_tile_regs(t + 1);           // always valid in main loop

        f32x4 s40[4];
        QKT_ONE({ mm[0] = 0.0f; mm[1] = 0.0f; mm[2] = 0.0f; mm[3] = 0.0f; });
        SM_PV_ONE();
    }

    // ---- peeled last tile: padded slots get -NEGL in the C-init ----
    {
        __syncthreads();
        write_tile_lds();
        __syncthreads();

        const int lastbase = (NTb - 1) * KT + 4 * g;
        f32x4 s40[4];
        QKT_ONE({
            int slot = lastbase + 16 * n;
            mm[0] = (slot + 0 < nv) ? 0.0f : -NEGL;
            mm[1] = (slot + 1 < nv) ? 0.0f : -NEGL;
            mm[2] = (slot + 2 < nv) ? 0.0f : -NEGL;
            mm[3] = (slot + 3 < nv) ? 0.0f : -NEGL;
        });
        SM_PV_ONE();
    }

    // ---- epilogue: O[q=4g+r][d=16dt+l15] /= l(q) ----
    {
        float inv = 1.0f / l0;
        float invq[4];
#pragma unroll
        for (int r = 0; r < 4; ++r) invq[r] = __shfl(inv, 4 * g + r);
        const size_t rowbase = (size_t)(bh * SS + qt * QB + w * 16);
#pragma unroll
        for (int dt = 0; dt < 4; ++dt)
#pragma unroll
            for (int r = 0; r < 4; ++r)
                Out[(rowbase + 4 * g + r) * DD + dt * 16 + l15] = Oacc0[dt][r] * invq[r];
    }
}

extern "C" void kernel_launch(void* const* d_in, const int* in_sizes, int n_in,
                              void* d_out, int out_size, void* d_ws, size_t ws_size,
                              hipStream_t stream) {
    const float* Q   = (const float*)d_in[0];
    const float* K   = (const float*)d_in[1];
    const float* V   = (const float*)d_in[2];
    const int* mask  = (const int*)d_in[5];
    float* out       = (float*)d_out;

    int* idxbuf = (int*)d_ws;                    // 8*1024 ints = 32 KB
    int* nvalid = idxbuf + 8 * SS;               // +8 ints

    prep_idx_kernel<<<dim3(8), 256, 0, stream>>>(mask, idxbuf, nvalid);
    attn_kernel<<<dim3(BH, NQT), 256, 0, stream>>>(Q, K, V, idxbuf, nvalid, out);
}

// Round 23
// 42.826 us; speedup vs baseline: 1.6343x; 1.1183x over previous
//
#include <hip/hip_runtime.h>
#include <hip/hip_bf16.h>
#include <cstdint>
#include <cstddef>

// Problem constants (B=8, H=12, S=1024, D=64)
#define HH 12
#define BH 96          // B*H
#define SS 1024
#define DD 64
#define KT 64          // keys per KV tile
#define QB 128         // q rows per block; 8 waves x 16 rows; grid 768 = 3 blk/CU = 24 waves/CU
#define NQT (SS / QB)  // 8

typedef __attribute__((ext_vector_type(2))) float f32x2;
typedef __attribute__((ext_vector_type(4))) float f32x4;
typedef __attribute__((ext_vector_type(8))) short bf16x8;
typedef __attribute__((ext_vector_type(4))) int   i32x4;

#define SCL  0.1803368801111204f   // 0.125 * log2(e)  -> exp2 domain
#define NEGL 1442695.0f            // 1e6  * log2(e)
#define THR  8.0f                  // defer-max threshold (log2 domain)

__device__ __forceinline__ unsigned int pk2(float lo, float hi) {
    __hip_bfloat162 h = __float22bfloat162_rn(float2{lo, hi});
    unsigned int u;
    __builtin_memcpy(&u, &h, sizeof(u));   // v_cvt_pk_bf16_f32
    return u;
}

// ===========================================================================
// prep_idx: compact valid-key indices per batch (verified rounds 18/20).
// Masked keys contribute EXACTLY 0 in the f32 reference (exp(-1e6) == 0.0f).
// All-masked edge case: identity mapping + nvalid=SS (shift-invariance).
// ===========================================================================
__global__ __launch_bounds__(256) void prep_idx_kernel(
        const int* __restrict__ mask,
        int* __restrict__ idxbuf,
        int* __restrict__ nvalid) {
    __shared__ int sc[256];
    const int b   = blockIdx.x;
    const int tid = threadIdx.x;
    i32x4 m = *(const i32x4*)(mask + b * SS + tid * 4);
    int keep[4];
    int c = 0;
#pragma unroll
    for (int j = 0; j < 4; ++j) { keep[j] = (m[j] != 0); c += keep[j]; }
    sc[tid] = c;
    __syncthreads();
    for (int off = 1; off < 256; off <<= 1) {
        int v = (tid >= off) ? sc[tid - off] : 0;
        __syncthreads();
        sc[tid] += v;
        __syncthreads();
    }
    const int total = sc[255];
    int pos = sc[tid] - c;
    int* dst = idxbuf + b * SS;
    if (total == 0) {
#pragma unroll
        for (int j = 0; j < 4; ++j) dst[tid * 4 + j] = tid * 4 + j;
        if (tid == 0) nvalid[b] = SS;
        return;
    }
#pragma unroll
    for (int j = 0; j < 4; ++j)
        if (keep[j]) dst[pos++] = tid * 4 + j;
    const int padded = (total + 63) & ~63;
    for (int s = total + tid; s < padded; s += 256) dst[s] = 0;
    if (tid == 0) nvalid[b] = total;
}

// ===========================================================================
// Flash attention over COMPACTED valid keys. Round-20 pipeline, restructured
// to 512-thread blocks: 8 waves x 16 q-rows = QB 128 per block, grid (96,8)
// = 768 blocks = 3 blk/CU = 24 waves/CU (r20: 12). Per-CU staging work is
// unchanged (same threads stage the same tiles); per-wave compute is the
// verified single-h form (r22 macros). V staging uses the d=lane mapping
// (rounds 4-11, measured 0 bank conflicts). Swapped QK^T, P in-register
// (permlane32+16 swap), defer-max, mask in MFMA C-init, peeled last tile,
// LDS swizzle col ^ ((row&7)<<3), schedule
// {barrier; write LDS(t); barrier; load(t+1); compute(t)}.
// ===========================================================================
__global__ __launch_bounds__(512, 6) void attn_kernel(
        const float* __restrict__ Q,
        const float* __restrict__ Kb,
        const float* __restrict__ Vb,
        const int* __restrict__ idxbuf,
        const int* __restrict__ nvalid,
        float* __restrict__ Out) {
    __shared__ unsigned short Klds[KT * DD];     // 8 KB
    __shared__ unsigned short Vlds[DD * KT];     // 8 KB
    __shared__ int idxLds[SS];                   // 4 KB

    const int tid  = threadIdx.x;                // 0..511
    const int w    = tid >> 6;                   // 0..7
    const int lane = tid & 63;
    const int g    = lane >> 4;
    const int l15  = lane & 15;
    const int swq  = (l15 & 7) << 3;

    const int bh = blockIdx.x;
    const int qt = blockIdx.y;
    const int b  = bh / HH;

    // ---- compacted-index table (256 threads cover all 1024 ints) ----
    if (tid < 256)
        ((i32x4*)idxLds)[tid] = ((const i32x4*)(idxbuf + b * SS))[tid];
    const int nv  = nvalid[b];
    const int NTb = (nv + 63) >> 6;

    // ---- Q fragments (B-operand of swapped QK^T), 16 rows per wave ----
    bf16x8 qa[2];
    {
        const float* qp = Q + ((size_t)(bh * SS + qt * QB + w * 16 + l15)) * DD + 8 * g;
#pragma unroll
        for (int c = 0; c < 2; ++c) {
            f32x4 lo = *(const f32x4*)(qp + c * 32);
            f32x4 hi = *(const f32x4*)(qp + c * 32 + 4);
            union { bf16x8 v; unsigned int u[4]; } o;
            o.u[0] = pk2(lo[0] * SCL, lo[1] * SCL);
            o.u[1] = pk2(lo[2] * SCL, lo[3] * SCL);
            o.u[2] = pk2(hi[0] * SCL, hi[1] * SCL);
            o.u[3] = pk2(hi[2] * SCL, hi[3] * SCL);
            qa[c] = o.v;
        }
    }

    // ---- staging registers: 512 threads cover the 64x64 tile once ----
    f32x4 kreg[2];                       // K[row=tid>>3][d0..d0+7], 32 B/thread
    float vreg[8];                       // V[k0+j][d=lane], 8 keys at fixed d
    const int krow_s = tid >> 3;         // K slot row
    const int kd0    = (tid & 7) * 8;    // K d-chunk
    const int vd     = lane;             // V d (coalesced across lanes)
    const int vk0    = w * 8;            // V 8-key chunk (wave-uniform)
    auto load_tile_regs = [&](int t) {
        {
            int krow = idxLds[t * KT + krow_s];
            const float* kp = Kb + ((size_t)(bh * SS + krow)) * DD + kd0;
            kreg[0] = *(const f32x4*)kp;
            kreg[1] = *(const f32x4*)(kp + 4);
        }
        {
            const float* vbase = Vb + (size_t)(bh * SS) * DD + vd;
#pragma unroll
            for (int j = 0; j < 8; ++j) {
                int vrow = idxLds[t * KT + vk0 + j];     // wave-uniform -> sgpr
                vreg[j] = vbase[(size_t)vrow * DD];
            }
        }
    };
    auto write_tile_lds = [&]() {
        {
            union { bf16x8 v; unsigned int u[4]; } kv;
            kv.u[0] = pk2(kreg[0][0], kreg[0][1]);
            kv.u[1] = pk2(kreg[0][2], kreg[0][3]);
            kv.u[2] = pk2(kreg[1][0], kreg[1][1]);
            kv.u[3] = pk2(kreg[1][2], kreg[1][3]);
            *(bf16x8*)&Klds[krow_s * DD + (kd0 ^ ((krow_s & 7) << 3))] = kv.v;
        }
        {
            union { bf16x8 v; unsigned int u[4]; } vv;
            vv.u[0] = pk2(vreg[0], vreg[1]);
            vv.u[1] = pk2(vreg[2], vreg[3]);
            vv.u[2] = pk2(vreg[4], vreg[5]);
            vv.u[3] = pk2(vreg[6], vreg[7]);
            *(bf16x8*)&Vlds[vd * KT + (vk0 ^ ((vd & 7) << 3))] = vv.v;
        }
    };

    f32x4 Oacc0[4];
#pragma unroll
    for (int dt = 0; dt < 4; ++dt) Oacc0[dt] = (f32x4){0.f, 0.f, 0.f, 0.f};
    float m0 = -3.0e38f, l0 = 0.f;

    __syncthreads();                     // idxLds visible to all waves
    load_tile_regs(0);

// softmax: s -> pk (bf16-packed P), updates mr/lr/Oa (verified r15-r22)
#define SOFTMAX_H(s, mr, lr, Oa, pk)                                          \
    do {                                                                      \
        float tmax;                                                           \
        {                                                                     \
            f32x4 mm = s[0];                                                  \
            _Pragma("unroll")                                                 \
            for (int n = 1; n < 4; ++n)                                       \
                _Pragma("unroll")                                             \
                for (int r = 0; r < 4; ++r) mm[r] = fmaxf(mm[r], s[n][r]);    \
            tmax = fmaxf(fmaxf(mm[0], mm[1]), fmaxf(mm[2], mm[3]));           \
        }                                                                     \
        tmax = fmaxf(tmax, __shfl_xor(tmax, 16));                             \
        tmax = fmaxf(tmax, __shfl_xor(tmax, 32));                             \
        if (!__all(tmax <= mr + THR)) {                                       \
            float mnew = fmaxf(mr, tmax);                                     \
            float corr = __builtin_amdgcn_exp2f(mr - mnew);                   \
            mr = mnew;                                                        \
            lr *= corr;                                                       \
            float cq[4];                                                      \
            _Pragma("unroll")                                                 \
            for (int r = 0; r < 4; ++r) cq[r] = __shfl(corr, 4 * g + r);      \
            _Pragma("unroll")                                                 \
            for (int dt = 0; dt < 4; ++dt)                                    \
                _Pragma("unroll")                                             \
                for (int r = 0; r < 4; ++r) Oa[dt][r] *= cq[r];               \
        }                                                                     \
        float tsum = 0.f;                                                     \
        _Pragma("unroll")                                                     \
        for (int n = 0; n < 4; ++n) {                                         \
            float p0 = __builtin_amdgcn_exp2f(s[n][0] - mr);                  \
            float p1 = __builtin_amdgcn_exp2f(s[n][1] - mr);                  \
            float p2 = __builtin_amdgcn_exp2f(s[n][2] - mr);                  \
            float p3 = __builtin_amdgcn_exp2f(s[n][3] - mr);                  \
            tsum += (p0 + p1) + (p2 + p3);                                    \
            pk[n][0] = pk2(p0, p1);                                           \
            pk[n][1] = pk2(p2, p3);                                           \
        }                                                                     \
        tsum += __shfl_xor(tsum, 16);                                         \
        tsum += __shfl_xor(tsum, 32);                                         \
        lr += tsum;                                                           \
    } while (0)

// rebuild PV A-fragment (permlane32_swap + permlane16_swap, verified r15)
#define REBUILD_PA(pk, ks, pa)                                                \
    do {                                                                      \
        auto sw0 = __builtin_amdgcn_permlane32_swap(pk[2 * ks][0], pk[2 * ks + 1][0], false, false); \
        auto sw1 = __builtin_amdgcn_permlane32_swap(pk[2 * ks][1], pk[2 * ks + 1][1], false, false); \
        auto sp0 = __builtin_amdgcn_permlane16_swap(sw0[0], sw0[1], false, false); \
        auto sp1 = __builtin_amdgcn_permlane16_swap(sw1[0], sw1[1], false, false); \
        pa.u[0] = sp0[0];                                                     \
        pa.u[2] = sp0[1];                                                     \
        pa.u[1] = sp1[0];                                                     \
        pa.u[3] = sp1[1];                                                     \
    } while (0)

// QK^T (swapped, single h per wave); MMSTMT sets f32x4 mm (the MFMA C-init)
#define QKT_ONE(MMSTMT)                                                       \
    __builtin_amdgcn_s_setprio(1);                                            \
    _Pragma("unroll")                                                         \
    for (int n = 0; n < 4; ++n) {                                             \
        f32x4 mm; MMSTMT;                                                     \
        bf16x8 kb0 = *(const bf16x8*)&Klds[(16 * n + l15) * DD + ((8 * g) ^ swq)]; \
        bf16x8 kb1 = *(const bf16x8*)&Klds[(16 * n + l15) * DD + ((32 + 8 * g) ^ swq)]; \
        f32x4 a0 = __builtin_amdgcn_mfma_f32_16x16x32_bf16(kb0, qa[0], mm, 0, 0, 0); \
        s40[n]   = __builtin_amdgcn_mfma_f32_16x16x32_bf16(kb1, qa[1], a0, 0, 0, 0); \
    }                                                                         \
    __builtin_amdgcn_s_setprio(0);

// softmax + PV (single h per wave)
#define SM_PV_ONE()                                                           \
    {                                                                         \
        unsigned int pk0[4][2];                                               \
        SOFTMAX_H(s40, m0, l0, Oacc0, pk0);                                   \
        __builtin_amdgcn_s_setprio(1);                                        \
        _Pragma("unroll")                                                     \
        for (int ks = 0; ks < 2; ++ks) {                                      \
            union { bf16x8 v; unsigned int u[4]; } pa0;                       \
            REBUILD_PA(pk0, ks, pa0);                                         \
            _Pragma("unroll")                                                 \
            for (int dt = 0; dt < 4; ++dt) {                                  \
                bf16x8 vb = *(const bf16x8*)                                  \
                    &Vlds[(dt * 16 + l15) * KT + ((ks * 32 + 8 * g) ^ swq)];  \
                Oacc0[dt] = __builtin_amdgcn_mfma_f32_16x16x32_bf16(pa0.v, vb, Oacc0[dt], 0, 0, 0); \
            }                                                                 \
        }                                                                     \
        __builtin_amdgcn_s_setprio(0);                                        \
    }

    // ---- main loop: tiles 0 .. NTb-2, zero C-init, unconditional prefetch ----
    for (int t = 0; t < NTb - 1; ++t) {
        __syncthreads();                 // all waves done reading tile t-1
        write_tile_lds();
        __syncthreads();                 // tile t visible
        load_tile_regs(t + 1);           // always valid in main loop

        f32x4 s40[4];
        QKT_ONE({ mm[0] = 0.0f; mm[1] = 0.0f; mm[2] = 0.0f; mm[3] = 0.0f; });
        SM_PV_ONE();
    }

    // ---- peeled last tile: padded slots get -NEGL in the C-init ----
    {
        __syncthreads();
        write_tile_lds();
        __syncthreads();

        const int lastbase = (NTb - 1) * KT + 4 * g;
        f32x4 s40[4];
        QKT_ONE({
            int slot = lastbase + 16 * n;
            mm[0] = (slot + 0 < nv) ? 0.0f : -NEGL;
            mm[1] = (slot + 1 < nv) ? 0.0f : -NEGL;
            mm[2] = (slot + 2 < nv) ? 0.0f : -NEGL;
            mm[3] = (slot + 3 < nv) ? 0.0f : -NEGL;
        });
        SM_PV_ONE();
    }

    // ---- epilogue: O[q=4g+r][d=16dt+l15] /= l(q) ----
    {
        float inv = 1.0f / l0;
        float invq[4];
#pragma unroll
        for (int r = 0; r < 4; ++r) invq[r] = __shfl(inv, 4 * g + r);
        const size_t rowbase = (size_t)(bh * SS + qt * QB + w * 16);
#pragma unroll
        for (int dt = 0; dt < 4; ++dt)
#pragma unroll
            for (int r = 0; r < 4; ++r)
                Out[(rowbase + 4 * g + r) * DD + dt * 16 + l15] = Oacc0[dt][r] * invq[r];
    }
}

extern "C" void kernel_launch(void* const* d_in, const int* in_sizes, int n_in,
                              void* d_out, int out_size, void* d_ws, size_t ws_size,
                              hipStream_t stream) {
    const float* Q   = (const float*)d_in[0];
    const float* K   = (const float*)d_in[1];
    const float* V   = (const float*)d_in[2];
    const int* mask  = (const int*)d_in[5];
    float* out       = (float*)d_out;

    int* idxbuf = (int*)d_ws;                    // 8*1024 ints = 32 KB
    int* nvalid = idxbuf + 8 * SS;               // +8 ints

    prep_idx_kernel<<<dim3(8), 256, 0, stream>>>(mask, idxbuf, nvalid);
    attn_kernel<<<dim3(BH, NQT), 512, 0, stream>>>(Q, K, V, idxbuf, nvalid, out);
}

// Round 24
// 38.977 us; speedup vs baseline: 1.7957x; 1.0987x over previous
//
#include <hip/hip_runtime.h>
#include <hip/hip_bf16.h>
#include <cstdint>
#include <cstddef>

// Problem constants (B=8, H=12, S=1024, D=64)
#define HH 12
#define BH 96          // B*H
#define SS 1024
#define DD 64
#define KT 64          // keys per KV tile
#define QB 128         // q rows per block (2 h-halves of 64; 32 q rows per wave)
#define NQT (SS / QB)  // 8

typedef __attribute__((ext_vector_type(2))) float f32x2;
typedef __attribute__((ext_vector_type(4))) float f32x4;
typedef __attribute__((ext_vector_type(8))) short bf16x8;
typedef __attribute__((ext_vector_type(4))) int   i32x4;

#define SCL  0.1803368801111204f   // 0.125 * log2(e)  -> exp2 domain
#define NEGL 1442695.0f            // 1e6  * log2(e)
#define THR  8.0f                  // defer-max threshold (log2 domain)

__device__ __forceinline__ unsigned int pk2(float lo, float hi) {
    __hip_bfloat162 h = __float22bfloat162_rn(float2{lo, hi});
    unsigned int u;
    __builtin_memcpy(&u, &h, sizeof(u));   // v_cvt_pk_bf16_f32
    return u;
}

// ===========================================================================
// Flash attention over COMPACTED valid keys — round-20 verified pipeline with
// the mask-compaction scan FUSED into each block (single dispatch; the 8-block
// prep_idx launch + inter-launch gap eliminated; scans run concurrently on
// all 768 blocks). Masked keys contribute EXACTLY 0 in the f32 reference
// (exp(-1e6) == 0.0f), so compacted attention is numerically identical;
// all-masked edge case degenerates to plain softmax via shift-invariance
// (identity mapping + nv = SS).
// Block = 4 waves, 128 q rows (two h-halves; K reads shared in QK^T, V reads
// shared in joint PV). grid = (bh, qt): same-bh blocks share an XCD.
// Schedule: barrier; write LDS(t); barrier; issue loads(t+1); compute(t).
// LDS swizzle (K and V): col ^ ((row&7)<<3). Last tile peeled (spill fix).
// ===========================================================================
__global__ __launch_bounds__(256, 3) void attn_kernel(
        const float* __restrict__ Q,
        const float* __restrict__ Kb,
        const float* __restrict__ Vb,
        const int* __restrict__ mask,
        float* __restrict__ Out) {
    __shared__ unsigned short Klds[KT * DD];     // 8 KB
    __shared__ unsigned short Vlds[DD * KT];     // 8 KB
    __shared__ int idxLds[SS];                   // 4 KB (compacted key table)
    __shared__ int sc[256];                      // 1 KB (scan workspace)

    const int tid  = threadIdx.x;
    const int w    = tid >> 6;
    const int lane = tid & 63;
    const int g    = lane >> 4;
    const int l15  = lane & 15;
    const int swq  = (l15 & 7) << 3;

    const int bh = blockIdx.x;
    const int qt = blockIdx.y;
    const int b  = bh / HH;

    // ---- fused mask compaction (verified prep_idx logic, output to LDS) ----
    int nv;
    {
        i32x4 m = *(const i32x4*)(mask + b * SS + tid * 4);
        int keep[4];
        int c = 0;
#pragma unroll
        for (int j = 0; j < 4; ++j) { keep[j] = (m[j] != 0); c += keep[j]; }
        sc[tid] = c;
        __syncthreads();
        for (int off = 1; off < 256; off <<= 1) {
            int v = (tid >= off) ? sc[tid - off] : 0;
            __syncthreads();
            sc[tid] += v;
            __syncthreads();
        }
        const int total = sc[255];
        int pos = sc[tid] - c;                  // exclusive prefix
        if (total == 0) {                       // all-masked: identity mapping
#pragma unroll
            for (int j = 0; j < 4; ++j) idxLds[tid * 4 + j] = tid * 4 + j;
            nv = SS;
        } else {
#pragma unroll
            for (int j = 0; j < 4; ++j)
                if (keep[j]) idxLds[pos++] = tid * 4 + j;
            const int padded = (total + 63) & ~63;
            for (int s = total + tid; s < padded; s += 256) idxLds[s] = 0;
            nv = total;
        }
    }
    const int NTb = (nv + 63) >> 6;

    // ---- Q fragments (B-operand of swapped QK^T), both halves, scaled ----
    bf16x8 qa[2][2];
#pragma unroll
    for (int h = 0; h < 2; ++h) {
        const float* qp = Q + ((size_t)(bh * SS + qt * QB + h * 64 + w * 16 + l15)) * DD + 8 * g;
#pragma unroll
        for (int c = 0; c < 2; ++c) {
            f32x4 lo = *(const f32x4*)(qp + c * 32);
            f32x4 hi = *(const f32x4*)(qp + c * 32 + 4);
            union { bf16x8 v; unsigned int u[4]; } o;
            o.u[0] = pk2(lo[0] * SCL, lo[1] * SCL);
            o.u[1] = pk2(lo[2] * SCL, lo[3] * SCL);
            o.u[2] = pk2(hi[0] * SCL, hi[1] * SCL);
            o.u[3] = pk2(hi[2] * SCL, hi[3] * SCL);
            qa[h][c] = o.v;
        }
    }

    // ---- staging registers (verified layout, gathered rows) ----
    f32x4 kreg[2][2];
    f32x2 vreg[8];                       // vreg[j] = V[key(vk0+j)][vd0..vd0+1]
    const int vd0 = (tid & 31) * 2;      // d-pair
    const int vk0 = (tid >> 5) * 8;      // 8-slot run
    auto load_tile_regs = [&](int t) {
#pragma unroll
        for (int i = 0; i < 2; ++i) {
            int c = tid + i * 256;       // K[slot][d0..d0+7]; row gathered via idxLds
            int row = c >> 3, d0 = (c & 7) * 8;
            int krow = idxLds[t * KT + row];
            const float* kp = Kb + ((size_t)(bh * SS + krow)) * DD + d0;
            kreg[i][0] = *(const f32x4*)kp;
            kreg[i][1] = *(const f32x4*)(kp + 4);
        }
        {   // V: 8 x f32x2 at gathered rows (each 256B row shared by 32 lanes)
            i32x4 vi0 = *(const i32x4*)&idxLds[t * KT + vk0];
            i32x4 vi1 = *(const i32x4*)&idxLds[t * KT + vk0 + 4];
            const float* vbase = Vb + (size_t)(bh * SS) * DD + vd0;
#pragma unroll
            for (int j = 0; j < 4; ++j) vreg[j]     = *(const f32x2*)(vbase + (size_t)vi0[j] * DD);
#pragma unroll
            for (int j = 0; j < 4; ++j) vreg[4 + j] = *(const f32x2*)(vbase + (size_t)vi1[j] * DD);
        }
    };
    auto write_tile_lds = [&]() {
#pragma unroll
        for (int i = 0; i < 2; ++i) {
            int c = tid + i * 256;
            int row = c >> 3, d0 = (c & 7) * 8;
            union { bf16x8 v; unsigned int u[4]; } kv;
            kv.u[0] = pk2(kreg[i][0][0], kreg[i][0][1]);
            kv.u[1] = pk2(kreg[i][0][2], kreg[i][0][3]);
            kv.u[2] = pk2(kreg[i][1][0], kreg[i][1][1]);
            kv.u[3] = pk2(kreg[i][1][2], kreg[i][1][3]);
            *(bf16x8*)&Klds[row * DD + (d0 ^ ((row & 7) << 3))] = kv.v;
        }
        {   // two V rows (d = vd0, vd0+1), slots vk0..vk0+7
            union { bf16x8 v; unsigned int u[4]; } v0, v1;
            v0.u[0] = pk2(vreg[0][0], vreg[1][0]);
            v0.u[1] = pk2(vreg[2][0], vreg[3][0]);
            v0.u[2] = pk2(vreg[4][0], vreg[5][0]);
            v0.u[3] = pk2(vreg[6][0], vreg[7][0]);
            v1.u[0] = pk2(vreg[0][1], vreg[1][1]);
            v1.u[1] = pk2(vreg[2][1], vreg[3][1]);
            v1.u[2] = pk2(vreg[4][1], vreg[5][1]);
            v1.u[3] = pk2(vreg[6][1], vreg[7][1]);
            *(bf16x8*)&Vlds[vd0 * KT + (vk0 ^ ((vd0 & 7) << 3))] = v0.v;
            *(bf16x8*)&Vlds[(vd0 + 1) * KT + (vk0 ^ (((vd0 + 1) & 7) << 3))] = v1.v;
        }
    };

    f32x4 Oacc0[4], Oacc1[4];
#pragma unroll
    for (int dt = 0; dt < 4; ++dt) {
        Oacc0[dt] = (f32x4){0.f, 0.f, 0.f, 0.f};
        Oacc1[dt] = (f32x4){0.f, 0.f, 0.f, 0.f};
    }
    float m0 = -3.0e38f, m1 = -3.0e38f, l0 = 0.f, l1 = 0.f;

    __syncthreads();                     // idxLds fully built & visible
    load_tile_regs(0);

// softmax for one h-half: s -> pk (bf16-packed P), updates mr/lr/Oa.
#define SOFTMAX_H(s, mr, lr, Oa, pk)                                          \
    do {                                                                      \
        float tmax;                                                           \
        {                                                                     \
            f32x4 mm = s[0];                                                  \
            _Pragma("unroll")                                                 \
            for (int n = 1; n < 4; ++n)                                       \
                _Pragma("unroll")                                             \
                for (int r = 0; r < 4; ++r) mm[r] = fmaxf(mm[r], s[n][r]);    \
            tmax = fmaxf(fmaxf(mm[0], mm[1]), fmaxf(mm[2], mm[3]));           \
        }                                                                     \
        tmax = fmaxf(tmax, __shfl_xor(tmax, 16));                             \
        tmax = fmaxf(tmax, __shfl_xor(tmax, 32));                             \
        if (!__all(tmax <= mr + THR)) {                                       \
            float mnew = fmaxf(mr, tmax);                                     \
            float corr = __builtin_amdgcn_exp2f(mr - mnew);                   \
            mr = mnew;                                                        \
            lr *= corr;                                                       \
            float cq[4];                                                      \
            _Pragma("unroll")                                                 \
            for (int r = 0; r < 4; ++r) cq[r] = __shfl(corr, 4 * g + r);      \
            _Pragma("unroll")                                                 \
            for (int dt = 0; dt < 4; ++dt)                                    \
                _Pragma("unroll")                                             \
                for (int r = 0; r < 4; ++r) Oa[dt][r] *= cq[r];               \
        }                                                                     \
        float tsum = 0.f;                                                     \
        _Pragma("unroll")                                                     \
        for (int n = 0; n < 4; ++n) {                                         \
            float p0 = __builtin_amdgcn_exp2f(s[n][0] - mr);                  \
            float p1 = __builtin_amdgcn_exp2f(s[n][1] - mr);                  \
            float p2 = __builtin_amdgcn_exp2f(s[n][2] - mr);                  \
            float p3 = __builtin_amdgcn_exp2f(s[n][3] - mr);                  \
            tsum += (p0 + p1) + (p2 + p3);                                    \
            pk[n][0] = pk2(p0, p1);                                           \
            pk[n][1] = pk2(p2, p3);                                           \
        }                                                                     \
        tsum += __shfl_xor(tsum, 16);                                         \
        tsum += __shfl_xor(tsum, 32);                                         \
        lr += tsum;                                                           \
    } while (0)

// rebuild PV A-fragment (permlane32_swap + permlane16_swap, verified r15)
#define REBUILD_PA(pk, ks, pa)                                                \
    do {                                                                      \
        auto sw0 = __builtin_amdgcn_permlane32_swap(pk[2 * ks][0], pk[2 * ks + 1][0], false, false); \
        auto sw1 = __builtin_amdgcn_permlane32_swap(pk[2 * ks][1], pk[2 * ks + 1][1], false, false); \
        auto sp0 = __builtin_amdgcn_permlane16_swap(sw0[0], sw0[1], false, false); \
        auto sp1 = __builtin_amdgcn_permlane16_swap(sw1[0], sw1[1], false, false); \
        pa.u[0] = sp0[0];                                                     \
        pa.u[2] = sp0[1];                                                     \
        pa.u[1] = sp1[0];                                                     \
        pa.u[3] = sp1[1];                                                     \
    } while (0)

// QK^T both halves over shared kb reads; MMSTMT sets f32x4 mm (the C-init)
#define QKT_BOTH(MMSTMT)                                                      \
    __builtin_amdgcn_s_setprio(1);                                            \
    _Pragma("unroll")                                                         \
    for (int n = 0; n < 4; ++n) {                                             \
        f32x4 mm; MMSTMT;                                                     \
        bf16x8 kb0 = *(const bf16x8*)&Klds[(16 * n + l15) * DD + ((8 * g) ^ swq)]; \
        bf16x8 kb1 = *(const bf16x8*)&Klds[(16 * n + l15) * DD + ((32 + 8 * g) ^ swq)]; \
        f32x4 a0 = __builtin_amdgcn_mfma_f32_16x16x32_bf16(kb0, qa[0][0], mm, 0, 0, 0); \
        s40[n]   = __builtin_amdgcn_mfma_f32_16x16x32_bf16(kb1, qa[0][1], a0, 0, 0, 0); \
        f32x4 a1 = __builtin_amdgcn_mfma_f32_16x16x32_bf16(kb0, qa[1][0], mm, 0, 0, 0); \
        s41[n]   = __builtin_amdgcn_mfma_f32_16x16x32_bf16(kb1, qa[1][1], a1, 0, 0, 0); \
    }                                                                         \
    __builtin_amdgcn_s_setprio(0);

// softmax + joint PV for both halves (vb read once, feeds both h)
#define SM_PV_BOTH()                                                          \
    {                                                                         \
        unsigned int pk0[4][2], pk1[4][2];                                    \
        SOFTMAX_H(s40, m0, l0, Oacc0, pk0);                                   \
        SOFTMAX_H(s41, m1, l1, Oacc1, pk1);                                   \
        __builtin_amdgcn_s_setprio(1);                                        \
        _Pragma("unroll")                                                     \
        for (int ks = 0; ks < 2; ++ks) {                                      \
            union { bf16x8 v; unsigned int u[4]; } pa0, pa1;                  \
            REBUILD_PA(pk0, ks, pa0);                                         \
            REBUILD_PA(pk1, ks, pa1);                                         \
            _Pragma("unroll")                                                 \
            for (int dt = 0; dt < 4; ++dt) {                                  \
                bf16x8 vb = *(const bf16x8*)                                  \
                    &Vlds[(dt * 16 + l15) * KT + ((ks * 32 + 8 * g) ^ swq)];  \
                Oacc0[dt] = __builtin_amdgcn_mfma_f32_16x16x32_bf16(pa0.v, vb, Oacc0[dt], 0, 0, 0); \
                Oacc1[dt] = __builtin_amdgcn_mfma_f32_16x16x32_bf16(pa1.v, vb, Oacc1[dt], 0, 0, 0); \
            }                                                                 \
        }                                                                     \
        __builtin_amdgcn_s_setprio(0);                                        \
    }

    // ---- main loop: tiles 0 .. NTb-2, zero C-init, unconditional prefetch ----
    for (int t = 0; t < NTb - 1; ++t) {
        __syncthreads();                 // all waves done reading tile t-1
        write_tile_lds();
        __syncthreads();                 // tile t visible
        load_tile_regs(t + 1);           // always valid in main loop

        f32x4 s40[4], s41[4];
        QKT_BOTH({ mm[0] = 0.0f; mm[1] = 0.0f; mm[2] = 0.0f; mm[3] = 0.0f; });
        SM_PV_BOTH();
    }

    // ---- peeled last tile: padded slots get -NEGL in the C-init ----
    {
        __syncthreads();
        write_tile_lds();
        __syncthreads();

        const int lastbase = (NTb - 1) * KT + 4 * g;
        f32x4 s40[4], s41[4];
        QKT_BOTH({
            int slot = lastbase + 16 * n;
            mm[0] = (slot + 0 < nv) ? 0.0f : -NEGL;
            mm[1] = (slot + 1 < nv) ? 0.0f : -NEGL;
            mm[2] = (slot + 2 < nv) ? 0.0f : -NEGL;
            mm[3] = (slot + 3 < nv) ? 0.0f : -NEGL;
        });
        SM_PV_BOTH();
    }

    // ---- epilogue: O[q=4g+r][d=16dt+l15] /= l(q), both halves ----
#pragma unroll
    for (int h = 0; h < 2; ++h) {
        float inv = 1.0f / (h ? l1 : l0);
        float invq[4];
#pragma unroll
        for (int r = 0; r < 4; ++r) invq[r] = __shfl(inv, 4 * g + r);
        const size_t rowbase = (size_t)(bh * SS + qt * QB + h * 64 + w * 16);
#pragma unroll
        for (int dt = 0; dt < 4; ++dt)
#pragma unroll
            for (int r = 0; r < 4; ++r)
                Out[(rowbase + 4 * g + r) * DD + dt * 16 + l15] =
                    (h ? Oacc1[dt][r] : Oacc0[dt][r]) * invq[r];
    }
}

extern "C" void kernel_launch(void* const* d_in, const int* in_sizes, int n_in,
                              void* d_out, int out_size, void* d_ws, size_t ws_size,
                              hipStream_t stream) {
    const float* Q   = (const float*)d_in[0];
    const float* K   = (const float*)d_in[1];
    const float* V   = (const float*)d_in[2];
    const int* mask  = (const int*)d_in[5];
    float* out       = (float*)d_out;

    attn_kernel<<<dim3(BH, NQT), 256, 0, stream>>>(Q, K, V, mask, out);
}

// Round 25
// 38.368 us; speedup vs baseline: 1.8242x; 1.0159x over previous
//
#include <hip/hip_runtime.h>
#include <hip/hip_bf16.h>
#include <cstdint>
#include <cstddef>

// Problem constants (B=8, H=12, S=1024, D=64)
#define HH 12
#define BH 96          // B*H
#define SS 1024
#define DD 64
#define KT 64          // keys per KV tile
#define QB 128         // q rows per block (2 h-halves of 64; 32 q rows per wave)
#define NQT (SS / QB)  // 8

typedef __attribute__((ext_vector_type(2))) float f32x2;
typedef __attribute__((ext_vector_type(4))) float f32x4;
typedef __attribute__((ext_vector_type(8))) short bf16x8;
typedef __attribute__((ext_vector_type(4))) int   i32x4;

#define SCL  0.1803368801111204f   // 0.125 * log2(e)  -> exp2 domain
#define NEGL 1442695.0f            // 1e6  * log2(e)
#define THR  8.0f                  // defer-max threshold (log2 domain)

__device__ __forceinline__ unsigned int pk2(float lo, float hi) {
    __hip_bfloat162 h = __float22bfloat162_rn(float2{lo, hi});
    unsigned int u;
    __builtin_memcpy(&u, &h, sizeof(u));   // v_cvt_pk_bf16_f32
    return u;
}

// ===========================================================================
// Flash attention over COMPACTED valid keys — round-24 verified pipeline with
// the in-block mask scan rewritten wave-parallel: intra-wave inclusive prefix
// via 6 shfl_up steps (register-only) + ONE barrier for the 4 wave totals
// (was 17 barriers of Hillis-Steele). Masked keys contribute EXACTLY 0 in the
// f32 reference (exp(-1e6) == 0.0f); all-masked edge degenerates to plain
// softmax via shift-invariance (identity mapping + nv = SS).
// Block = 4 waves, 128 q rows (two h-halves; K reads shared in QK^T, V reads
// shared in joint PV). grid = (bh, qt): same-bh blocks share an XCD.
// Schedule: barrier; write LDS(t); barrier; issue loads(t+1); compute(t).
// LDS swizzle (K and V): col ^ ((row&7)<<3). Last tile peeled (spill fix).
// ===========================================================================
__global__ __launch_bounds__(256, 3) void attn_kernel(
        const float* __restrict__ Q,
        const float* __restrict__ Kb,
        const float* __restrict__ Vb,
        const int* __restrict__ mask,
        float* __restrict__ Out) {
    __shared__ unsigned short Klds[KT * DD];     // 8 KB
    __shared__ unsigned short Vlds[DD * KT];     // 8 KB
    __shared__ int idxLds[SS];                   // 4 KB (compacted key table)
    __shared__ int wsum[4];                      // wave totals for the scan

    const int tid  = threadIdx.x;
    const int w    = tid >> 6;
    const int lane = tid & 63;
    const int g    = lane >> 4;
    const int l15  = lane & 15;
    const int swq  = (l15 & 7) << 3;

    const int bh = blockIdx.x;
    const int qt = blockIdx.y;
    const int b  = bh / HH;

    // ---- fused mask compaction: wave-parallel scan (2 barriers total) ----
    int nv;
    {
        i32x4 m = *(const i32x4*)(mask + b * SS + tid * 4);
        int keep[4];
        int c = 0;
#pragma unroll
        for (int j = 0; j < 4; ++j) { keep[j] = (m[j] != 0); c += keep[j]; }
        // intra-wave inclusive prefix over per-thread counts (no barriers)
        int pref = c;
#pragma unroll
        for (int off = 1; off < 64; off <<= 1) {
            int v = __shfl_up(pref, off);
            if (lane >= off) pref += v;
        }
        if (lane == 63) wsum[w] = pref;
        __syncthreads();
        int waveoff = 0;
#pragma unroll
        for (int i = 0; i < 4; ++i) waveoff += (i < w) ? wsum[i] : 0;
        const int total = wsum[0] + wsum[1] + wsum[2] + wsum[3];
        int pos = waveoff + pref - c;           // exclusive prefix
        if (total == 0) {                       // all-masked: identity mapping
#pragma unroll
            for (int j = 0; j < 4; ++j) idxLds[tid * 4 + j] = tid * 4 + j;
            nv = SS;
        } else {
#pragma unroll
            for (int j = 0; j < 4; ++j)
                if (keep[j]) idxLds[pos++] = tid * 4 + j;
            const int padded = (total + 63) & ~63;
            for (int s = total + tid; s < padded; s += 256) idxLds[s] = 0;
            nv = total;
        }
    }
    const int NTb = (nv + 63) >> 6;

    // ---- Q fragments (B-operand of swapped QK^T), both halves, scaled ----
    bf16x8 qa[2][2];
#pragma unroll
    for (int h = 0; h < 2; ++h) {
        const float* qp = Q + ((size_t)(bh * SS + qt * QB + h * 64 + w * 16 + l15)) * DD + 8 * g;
#pragma unroll
        for (int c = 0; c < 2; ++c) {
            f32x4 lo = *(const f32x4*)(qp + c * 32);
            f32x4 hi = *(const f32x4*)(qp + c * 32 + 4);
            union { bf16x8 v; unsigned int u[4]; } o;
            o.u[0] = pk2(lo[0] * SCL, lo[1] * SCL);
            o.u[1] = pk2(lo[2] * SCL, lo[3] * SCL);
            o.u[2] = pk2(hi[0] * SCL, hi[1] * SCL);
            o.u[3] = pk2(hi[2] * SCL, hi[3] * SCL);
            qa[h][c] = o.v;
        }
    }

    // ---- staging registers (verified layout, gathered rows) ----
    f32x4 kreg[2][2];
    f32x2 vreg[8];                       // vreg[j] = V[key(vk0+j)][vd0..vd0+1]
    const int vd0 = (tid & 31) * 2;      // d-pair
    const int vk0 = (tid >> 5) * 8;      // 8-slot run
    auto load_tile_regs = [&](int t) {
#pragma unroll
        for (int i = 0; i < 2; ++i) {
            int c = tid + i * 256;       // K[slot][d0..d0+7]; row gathered via idxLds
            int row = c >> 3, d0 = (c & 7) * 8;
            int krow = idxLds[t * KT + row];
            const float* kp = Kb + ((size_t)(bh * SS + krow)) * DD + d0;
            kreg[i][0] = *(const f32x4*)kp;
            kreg[i][1] = *(const f32x4*)(kp + 4);
        }
        {   // V: 8 x f32x2 at gathered rows (each 256B row shared by 32 lanes)
            i32x4 vi0 = *(const i32x4*)&idxLds[t * KT + vk0];
            i32x4 vi1 = *(const i32x4*)&idxLds[t * KT + vk0 + 4];
            const float* vbase = Vb + (size_t)(bh * SS) * DD + vd0;
#pragma unroll
            for (int j = 0; j < 4; ++j) vreg[j]     = *(const f32x2*)(vbase + (size_t)vi0[j] * DD);
#pragma unroll
            for (int j = 0; j < 4; ++j) vreg[4 + j] = *(const f32x2*)(vbase + (size_t)vi1[j] * DD);
        }
    };
    auto write_tile_lds = [&]() {
#pragma unroll
        for (int i = 0; i < 2; ++i) {
            int c = tid + i * 256;
            int row = c >> 3, d0 = (c & 7) * 8;
            union { bf16x8 v; unsigned int u[4]; } kv;
            kv.u[0] = pk2(kreg[i][0][0], kreg[i][0][1]);
            kv.u[1] = pk2(kreg[i][0][2], kreg[i][0][3]);
            kv.u[2] = pk2(kreg[i][1][0], kreg[i][1][1]);
            kv.u[3] = pk2(kreg[i][1][2], kreg[i][1][3]);
            *(bf16x8*)&Klds[row * DD + (d0 ^ ((row & 7) << 3))] = kv.v;
        }
        {   // two V rows (d = vd0, vd0+1), slots vk0..vk0+7
            union { bf16x8 v; unsigned int u[4]; } v0, v1;
            v0.u[0] = pk2(vreg[0][0], vreg[1][0]);
            v0.u[1] = pk2(vreg[2][0], vreg[3][0]);
            v0.u[2] = pk2(vreg[4][0], vreg[5][0]);
            v0.u[3] = pk2(vreg[6][0], vreg[7][0]);
            v1.u[0] = pk2(vreg[0][1], vreg[1][1]);
            v1.u[1] = pk2(vreg[2][1], vreg[3][1]);
            v1.u[2] = pk2(vreg[4][1], vreg[5][1]);
            v1.u[3] = pk2(vreg[6][1], vreg[7][1]);
            *(bf16x8*)&Vlds[vd0 * KT + (vk0 ^ ((vd0 & 7) << 3))] = v0.v;
            *(bf16x8*)&Vlds[(vd0 + 1) * KT + (vk0 ^ (((vd0 + 1) & 7) << 3))] = v1.v;
        }
    };

    f32x4 Oacc0[4], Oacc1[4];
#pragma unroll
    for (int dt = 0; dt < 4; ++dt) {
        Oacc0[dt] = (f32x4){0.f, 0.f, 0.f, 0.f};
        Oacc1[dt] = (f32x4){0.f, 0.f, 0.f, 0.f};
    }
    float m0 = -3.0e38f, m1 = -3.0e38f, l0 = 0.f, l1 = 0.f;

    __syncthreads();                     // idxLds fully built & visible
    load_tile_regs(0);

// softmax for one h-half: s -> pk (bf16-packed P), updates mr/lr/Oa.
#define SOFTMAX_H(s, mr, lr, Oa, pk)                                          \
    do {                                                                      \
        float tmax;                                                           \
        {                                                                     \
            f32x4 mm = s[0];                                                  \
            _Pragma("unroll")                                                 \
            for (int n = 1; n < 4; ++n)                                       \
                _Pragma("unroll")                                             \
                for (int r = 0; r < 4; ++r) mm[r] = fmaxf(mm[r], s[n][r]);    \
            tmax = fmaxf(fmaxf(mm[0], mm[1]), fmaxf(mm[2], mm[3]));           \
        }                                                                     \
        tmax = fmaxf(tmax, __shfl_xor(tmax, 16));                             \
        tmax = fmaxf(tmax, __shfl_xor(tmax, 32));                             \
        if (!__all(tmax <= mr + THR)) {                                       \
            float mnew = fmaxf(mr, tmax);                                     \
            float corr = __builtin_amdgcn_exp2f(mr - mnew);                   \
            mr = mnew;                                                        \
            lr *= corr;                                                       \
            float cq[4];                                                      \
            _Pragma("unroll")                                                 \
            for (int r = 0; r < 4; ++r) cq[r] = __shfl(corr, 4 * g + r);      \
            _Pragma("unroll")                                                 \
            for (int dt = 0; dt < 4; ++dt)                                    \
                _Pragma("unroll")                                             \
                for (int r = 0; r < 4; ++r) Oa[dt][r] *= cq[r];               \
        }                                                                     \
        float tsum = 0.f;                                                     \
        _Pragma("unroll")                                                     \
        for (int n = 0; n < 4; ++n) {                                         \
            float p0 = __builtin_amdgcn_exp2f(s[n][0] - mr);                  \
            float p1 = __builtin_amdgcn_exp2f(s[n][1] - mr);                  \
            float p2 = __builtin_amdgcn_exp2f(s[n][2] - mr);                  \
            float p3 = __builtin_amdgcn_exp2f(s[n][3] - mr);                  \
            tsum += (p0 + p1) + (p2 + p3);                                    \
            pk[n][0] = pk2(p0, p1);                                           \
            pk[n][1] = pk2(p2, p3);                                           \
        }                                                                     \
        tsum += __shfl_xor(tsum, 16);                                         \
        tsum += __shfl_xor(tsum, 32);                                         \
        lr += tsum;                                                           \
    } while (0)

// rebuild PV A-fragment (permlane32_swap + permlane16_swap, verified r15)
#define REBUILD_PA(pk, ks, pa)                                                \
    do {                                                                      \
        auto sw0 = __builtin_amdgcn_permlane32_swap(pk[2 * ks][0], pk[2 * ks + 1][0], false, false); \
        auto sw1 = __builtin_amdgcn_permlane32_swap(pk[2 * ks][1], pk[2 * ks + 1][1], false, false); \
        auto sp0 = __builtin_amdgcn_permlane16_swap(sw0[0], sw0[1], false, false); \
        auto sp1 = __builtin_amdgcn_permlane16_swap(sw1[0], sw1[1], false, false); \
        pa.u[0] = sp0[0];                                                     \
        pa.u[2] = sp0[1];                                                     \
        pa.u[1] = sp1[0];                                                     \
        pa.u[3] = sp1[1];                                                     \
    } while (0)

// QK^T both halves over shared kb reads; MMSTMT sets f32x4 mm (the C-init)
#define QKT_BOTH(MMSTMT)                                                      \
    __builtin_amdgcn_s_setprio(1);                                            \
    _Pragma("unroll")                                                         \
    for (int n = 0; n < 4; ++n) {                                             \
        f32x4 mm; MMSTMT;                                                     \
        bf16x8 kb0 = *(const bf16x8*)&Klds[(16 * n + l15) * DD + ((8 * g) ^ swq)]; \
        bf16x8 kb1 = *(const bf16x8*)&Klds[(16 * n + l15) * DD + ((32 + 8 * g) ^ swq)]; \
        f32x4 a0 = __builtin_amdgcn_mfma_f32_16x16x32_bf16(kb0, qa[0][0], mm, 0, 0, 0); \
        s40[n]   = __builtin_amdgcn_mfma_f32_16x16x32_bf16(kb1, qa[0][1], a0, 0, 0, 0); \
        f32x4 a1 = __builtin_amdgcn_mfma_f32_16x16x32_bf16(kb0, qa[1][0], mm, 0, 0, 0); \
        s41[n]   = __builtin_amdgcn_mfma_f32_16x16x32_bf16(kb1, qa[1][1], a1, 0, 0, 0); \
    }                                                                         \
    __builtin_amdgcn_s_setprio(0);

// softmax + joint PV for both halves (vb read once, feeds both h)
#define SM_PV_BOTH()                                                          \
    {                                                                         \
        unsigned int pk0[4][2], pk1[4][2];                                    \
        SOFTMAX_H(s40, m0, l0, Oacc0, pk0);                                   \
        SOFTMAX_H(s41, m1, l1, Oacc1, pk1);                                   \
        __builtin_amdgcn_s_setprio(1);                                        \
        _Pragma("unroll")                                                     \
        for (int ks = 0; ks < 2; ++ks) {                                      \
            union { bf16x8 v; unsigned int u[4]; } pa0, pa1;                  \
            REBUILD_PA(pk0, ks, pa0);                                         \
            REBUILD_PA(pk1, ks, pa1);                                         \
            _Pragma("unroll")                                                 \
            for (int dt = 0; dt < 4; ++dt) {                                  \
                bf16x8 vb = *(const bf16x8*)                                  \
                    &Vlds[(dt * 16 + l15) * KT + ((ks * 32 + 8 * g) ^ swq)];  \
                Oacc0[dt] = __builtin_amdgcn_mfma_f32_16x16x32_bf16(pa0.v, vb, Oacc0[dt], 0, 0, 0); \
                Oacc1[dt] = __builtin_amdgcn_mfma_f32_16x16x32_bf16(pa1.v, vb, Oacc1[dt], 0, 0, 0); \
            }                                                                 \
        }                                                                     \
        __builtin_amdgcn_s_setprio(0);                                        \
    }

    // ---- main loop: tiles 0 .. NTb-2, zero C-init, unconditional prefetch ----
    for (int t = 0; t < NTb - 1; ++t) {
        __syncthreads();                 // all waves done reading tile t-1
        write_tile_lds();
        __syncthreads();                 // tile t visible
        load_tile_regs(t + 1);           // always valid in main loop

        f32x4 s40[4], s41[4];
        QKT_BOTH({ mm[0] = 0.0f; mm[1] = 0.0f; mm[2] = 0.0f; mm[3] = 0.0f; });
        SM_PV_BOTH();
    }

    // ---- peeled last tile: padded slots get -NEGL in the C-init ----
    {
        __syncthreads();
        write_tile_lds();
        __syncthreads();

        const int lastbase = (NTb - 1) * KT + 4 * g;
        f32x4 s40[4], s41[4];
        QKT_BOTH({
            int slot = lastbase + 16 * n;
            mm[0] = (slot + 0 < nv) ? 0.0f : -NEGL;
            mm[1] = (slot + 1 < nv) ? 0.0f : -NEGL;
            mm[2] = (slot + 2 < nv) ? 0.0f : -NEGL;
            mm[3] = (slot + 3 < nv) ? 0.0f : -NEGL;
        });
        SM_PV_BOTH();
    }

    // ---- epilogue: O[q=4g+r][d=16dt+l15] /= l(q), both halves ----
#pragma unroll
    for (int h = 0; h < 2; ++h) {
        float inv = 1.0f / (h ? l1 : l0);
        float invq[4];
#pragma unroll
        for (int r = 0; r < 4; ++r) invq[r] = __shfl(inv, 4 * g + r);
        const size_t rowbase = (size_t)(bh * SS + qt * QB + h * 64 + w * 16);
#pragma unroll
        for (int dt = 0; dt < 4; ++dt)
#pragma unroll
            for (int r = 0; r < 4; ++r)
                Out[(rowbase + 4 * g + r) * DD + dt * 16 + l15] =
                    (h ? Oacc1[dt][r] : Oacc0[dt][r]) * invq[r];
    }
}

extern "C" void kernel_launch(void* const* d_in, const int* in_sizes, int n_in,
                              void* d_out, int out_size, void* d_ws, size_t ws_size,
                              hipStream_t stream) {
    const float* Q   = (const float*)d_in[0];
    const float* K   = (const float*)d_in[1];
    const float* V   = (const float*)d_in[2];
    const int* mask  = (const int*)d_in[5];
    float* out       = (float*)d_out;

    attn_kernel<<<dim3(BH, NQT), 256, 0, stream>>>(Q, K, V, mask, out);
}